// Round 11
// baseline (292.888 us; speedup 1.0000x reference)
//
#include <hip/hip_runtime.h>

// ---------------------------------------------------------------------------
// MaskedAutoregressiveFlow (RealNVP coupling) fused kernel for gfx950. R11.
// B=16384 rows, F=64, CTX=128, HID=512, L=8 layers, NB=2 hidden blocks.
//
// R11 = R10 (full fp8) with the GEMM orientation TRANSPOSED: h'^T = W^T h^T.
//  - A operand = weights (same fragment packing as R10's B), B operand = h
//    read from row-major LDS (same contiguous 8B reads as R10's A).
//  - C/D now gives each lane a batch-row slice with n' in runs of 4:
//    epilogue = 8 ds_write_b32 + 16 cvt_pk (was 32 ds_write_b8 + 32 cvt).
//  - G3 transposed: acc0 = shift cols, acc1 = scale cols in the SAME thread
//    -> coupling fully in registers, p never in LDS, one barrier saved.
//    2 waves own G3+coupling; logdet pairs via shfl_down(32).
//  - ctx (128 of 160 G0-input cols) is layer-invariant: staged ONCE in abuf.
//  - xbuf row stride 68 floats to de-alias coupling column writes.
// ---------------------------------------------------------------------------

typedef float v16f __attribute__((ext_vector_type(16)));
typedef unsigned char uchar;
typedef unsigned long long ull;

#define BATCH 16384
#define NF    64
#define NCTX  128
#define NL    8

#define RS    520   // h row stride (bytes, fp8)
#define AST   168   // [id|ctx] input row stride (bytes, fp8)
#define XST   68    // xbuf row stride (floats)

#define WSCALE     16.0f
#define WSCALE_INV 0.0625f

// packed-weight offsets (fp8 elements = bytes)
#define WIN_EPL   (160 * 512)
#define WH_EPB    (512 * 512)
#define WOUT_EPL  (512 * 64)
#define OFF_WIN   ((size_t)0)
#define OFF_WH    ((size_t)(8 * WIN_EPL))
#define OFF_WOUT  (OFF_WH + (size_t)(16 * WH_EPB))
#define TOT_PACK_ELEMS (OFF_WOUT + (size_t)(8 * WOUT_EPL))
#define NEED_WS   (TOT_PACK_ELEMS)

template<bool HI>
__device__ __forceinline__ unsigned int pk2(float a, float b, unsigned int old) {
    return __builtin_amdgcn_cvt_pk_fp8_f32(a, b, old, HI);
}

// ---------------------------------------------------------------------------
// pack: fp32 -> fp8 e4m3 (x16), DESTINATION-ordered (one 8B store/thread).
// W_in/W_h -> 32x32x16 A-frag order (same indexing as R10): frag = kc*16+st;
//   lane l: k = kc*16 + (l>>5)*8 + j, n' = st*32 + (l&31).
// W_out -> 32x32x16 A-frag order for G3: frag = kc*2 + st;
//   lane l: k = kc*16 + (l>>5)*8 + j, n' = st*32 + (l&31).
// ---------------------------------------------------------------------------
__global__ void pack_weights_kernel(const float* __restrict__ W_in,
                                    const float* __restrict__ W_h,
                                    const float* __restrict__ W_out,
                                    unsigned char* __restrict__ ws) {
    const int TIN  = 8 * (WIN_EPL / 8);     // 81920
    const int TH   = 16 * (WH_EPB / 8);     // 524288
    const int TOUT = 8 * (WOUT_EPL / 8);    // 32768
    int t = blockIdx.x * blockDim.x + threadIdx.x;
    if (t >= TIN + TH + TOUT) return;
    float v[8];
    if (t < TIN + TH) {
        const float* src; int r;
        if (t < TIN) {
            int i = t / (WIN_EPL / 8); r = t - i * (WIN_EPL / 8);
            src = W_in + (size_t)i * WIN_EPL;
        } else {
            int u = t - TIN; int ij = u >> 15; r = u & 32767;
            src = W_h + (size_t)ij * WH_EPB;
        }
        int frag = r >> 6, lane = r & 63;
        int k0 = (frag >> 4) * 16 + (lane >> 5) * 8;
        int n  = (frag & 15) * 32 + (lane & 31);
#pragma unroll
        for (int j = 0; j < 8; ++j)
            v[j] = src[(size_t)(k0 + j) * 512 + n] * WSCALE;
    } else {
        int u = t - TIN - TH;
        int i = u >> 12, r = u & 4095;
        const float* src = W_out + (size_t)i * WOUT_EPL;
        int frag = r >> 6, lane = r & 63;        // frag = kc*2 + strip
        int k0 = (frag >> 1) * 16 + (lane >> 5) * 8;
        int n  = (frag & 1) * 32 + (lane & 31);
#pragma unroll
        for (int j = 0; j < 8; ++j)
            v[j] = src[(size_t)(k0 + j) * 64 + n] * WSCALE;
    }
    uint2 o;
    o.x = pk2<false>(v[0], v[1], 0u);
    o.x = pk2<true >(v[2], v[3], o.x);
    o.y = pk2<false>(v[4], v[5], 0u);
    o.y = pk2<true >(v[6], v[7], o.y);
    *(uint2*)(ws + (size_t)t * 8) = o;
}

__device__ __forceinline__ v16f mfma32(ull a, ull b, v16f c) {
    return __builtin_amdgcn_mfma_f32_32x32x16_fp8_fp8((long)a, (long)b, c, 0, 0, 0);
}

// ---------------------------------------------------------------------------
// Transposed 32x32x16 fp8 stage: computes h'[m][n'] for one n'-strip (32)
// over all 64 batch rows. A = weight frags (global, D=4 pipeline),
// B = h frags (row-major LDS, contiguous 8B/lane).
// Epilogue: n' runs of 4 -> packed dword LDS writes.
// ---------------------------------------------------------------------------
template<int KC, bool PACKED>
__device__ __forceinline__ void gemm32T(
    const uchar* __restrict__ wpk,
    const float* __restrict__ wraw,    // raw fp32 [K][512] fallback
    const float* __restrict__ bias,
    const uchar* __restrict__ Bh, int bst,
    uchar* __restrict__ Oh, int ost,
    int strip, int lane)
{
    const int l31 = lane & 31, hl = lane >> 5;
    v16f acc0, acc1;
#pragma unroll
    for (int r = 0; r < 16; ++r) { acc0[r] = 0.f; acc1[r] = 0.f; }
    const uchar* b0p = Bh + l31 * bst + hl * 8;   // batch rows 0..31
    const uchar* b1p = b0p + 32 * bst;            // batch rows 32..63
    const uchar* aptr =
        PACKED ? wpk + (size_t)(strip * 64 + lane) * 8 : (const uchar*)0;

    auto loadA = [&](int idx) -> ull {
        if constexpr (PACKED) {
            return *(const ull*)(aptr + (size_t)idx * 8192);  // 16 strips x 512B
        } else {
            int np = strip * 32 + l31;
            int k0 = idx * 16 + hl * 8;
            unsigned int lo, hi;
            lo = pk2<false>(wraw[(size_t)(k0 + 0) * 512 + np] * WSCALE,
                            wraw[(size_t)(k0 + 1) * 512 + np] * WSCALE, 0u);
            lo = pk2<true >(wraw[(size_t)(k0 + 2) * 512 + np] * WSCALE,
                            wraw[(size_t)(k0 + 3) * 512 + np] * WSCALE, lo);
            hi = pk2<false>(wraw[(size_t)(k0 + 4) * 512 + np] * WSCALE,
                            wraw[(size_t)(k0 + 5) * 512 + np] * WSCALE, 0u);
            hi = pk2<true >(wraw[(size_t)(k0 + 6) * 512 + np] * WSCALE,
                            wraw[(size_t)(k0 + 7) * 512 + np] * WSCALE, hi);
            return ((ull)hi << 32) | (ull)lo;
        }
    };
    auto step = [&](int kc, ull aw) {
        ull b0 = *(const ull*)(b0p + kc * 16);
        ull b1 = *(const ull*)(b1p + kc * 16);
        acc0 = mfma32(aw, b0, acc0);
        acc1 = mfma32(aw, b1, acc1);
    };

    ull a0 = loadA(0), a1 = loadA(1), a2 = loadA(2), a3 = loadA(3);
    int kc = 0;
#pragma unroll 1
    for (; kc + 3 < KC; kc += 4) {
        step(kc + 0, a0); if (kc + 4 < KC) a0 = loadA(kc + 4);
        step(kc + 1, a1); if (kc + 5 < KC) a1 = loadA(kc + 5);
        step(kc + 2, a2); if (kc + 6 < KC) a2 = loadA(kc + 6);
        step(kc + 3, a3); if (kc + 7 < KC) a3 = loadA(kc + 7);
    }
    if (kc     < KC) step(kc,     a0);
    if (kc + 1 < KC) step(kc + 1, a1);
    if (kc + 2 < KC) step(kc + 2, a2);

    // epilogue: C^T layout -> lane owns batch row m = bt*32+l31 (col),
    // n' = strip*32 + rq*8 + hl*4 + i (row). 4 consecutive n' per reg-quad.
    const float* bs = bias + strip * 32;
#pragma unroll
    for (int bt = 0; bt < 2; ++bt) {
        const v16f& ac = bt ? acc1 : acc0;
        uchar* orow = Oh + (bt * 32 + l31) * ost + strip * 32;
#pragma unroll
        for (int rq = 0; rq < 4; ++rq) {
            int nb = rq * 8 + hl * 4;
            float4 bv = *(const float4*)(bs + nb);
            float v0 = fmaxf(fmaf(ac[rq * 4 + 0], WSCALE_INV, bv.x), 0.f);
            float v1 = fmaxf(fmaf(ac[rq * 4 + 1], WSCALE_INV, bv.y), 0.f);
            float v2 = fmaxf(fmaf(ac[rq * 4 + 2], WSCALE_INV, bv.z), 0.f);
            float v3 = fmaxf(fmaf(ac[rq * 4 + 3], WSCALE_INV, bv.w), 0.f);
            unsigned int d = pk2<false>(v0, v1, 0u);
            d = pk2<true>(v2, v3, d);
            *(unsigned int*)(orow + nb) = d;
        }
    }
}

// ---------------------------------------------------------------------------
// G3 + coupling, transposed: p^T = W_out^T h^T for one batch tile (bt).
// acc0 = p cols 0..31 (shift), acc1 = cols 32..63 (scale) -> coupling fully
// in registers. Returns this thread's logdet partial for the layer.
// ---------------------------------------------------------------------------
template<bool PACKED>
__device__ __forceinline__ float gemm3_couple(
    const uchar* __restrict__ wpk,
    const float* __restrict__ wraw,    // raw fp32 W_out [512][64]
    const float* __restrict__ b_out,
    const uchar* __restrict__ Bh,
    float* __restrict__ xbuf,
    int par, int bt, int lane)
{
    const int l31 = lane & 31, hl = lane >> 5;
    v16f acc0, acc1;
#pragma unroll
    for (int r = 0; r < 16; ++r) { acc0[r] = 0.f; acc1[r] = 0.f; }
    const uchar* bp = Bh + (bt * 32 + l31) * RS + hl * 8;
    const uchar* aptr = PACKED ? wpk + (size_t)lane * 8 : (const uchar*)0;
    constexpr int KC = 32;

    auto loadA = [&](int idx, int strip) -> ull {
        if constexpr (PACKED) {
            return *(const ull*)(aptr + (size_t)(idx * 2 + strip) * 512);
        } else {
            int np = strip * 32 + l31;
            int k0 = idx * 16 + hl * 8;
            unsigned int lo, hi;
            lo = pk2<false>(wraw[(size_t)(k0 + 0) * 64 + np] * WSCALE,
                            wraw[(size_t)(k0 + 1) * 64 + np] * WSCALE, 0u);
            lo = pk2<true >(wraw[(size_t)(k0 + 2) * 64 + np] * WSCALE,
                            wraw[(size_t)(k0 + 3) * 64 + np] * WSCALE, lo);
            hi = pk2<false>(wraw[(size_t)(k0 + 4) * 64 + np] * WSCALE,
                            wraw[(size_t)(k0 + 5) * 64 + np] * WSCALE, 0u);
            hi = pk2<true >(wraw[(size_t)(k0 + 6) * 64 + np] * WSCALE,
                            wraw[(size_t)(k0 + 7) * 64 + np] * WSCALE, hi);
            return ((ull)hi << 32) | (ull)lo;
        }
    };
    auto step = [&](int kc, ull a0, ull a1) {
        ull b = *(const ull*)(bp + kc * 16);
        acc0 = mfma32(a0, b, acc0);
        acc1 = mfma32(a1, b, acc1);
    };

    ull p00 = loadA(0, 0), p01 = loadA(0, 1);
    ull p10 = loadA(1, 0), p11 = loadA(1, 1);
    ull p20 = loadA(2, 0), p21 = loadA(2, 1);
    ull p30 = loadA(3, 0), p31 = loadA(3, 1);
    int kc = 0;
#pragma unroll 1
    for (; kc + 3 < KC; kc += 4) {
        step(kc + 0, p00, p01);
        if (kc + 4 < KC) { p00 = loadA(kc + 4, 0); p01 = loadA(kc + 4, 1); }
        step(kc + 1, p10, p11);
        if (kc + 5 < KC) { p10 = loadA(kc + 5, 0); p11 = loadA(kc + 5, 1); }
        step(kc + 2, p20, p21);
        if (kc + 6 < KC) { p20 = loadA(kc + 6, 0); p21 = loadA(kc + 6, 1); }
        step(kc + 3, p30, p31);
        if (kc + 7 < KC) { p30 = loadA(kc + 7, 0); p31 = loadA(kc + 7, 1); }
    }

    // coupling: sc = n' of acc0-reg; scale input at n' = 32+sc in acc1-reg.
    float ld = 0.f;
    float* xr = xbuf + (bt * 32 + l31) * XST;
#pragma unroll
    for (int reg = 0; reg < 16; ++reg) {
        int sc = (reg & 3) + 8 * (reg >> 2) + 4 * hl;
        float shiftv = fmaf(acc0[reg], WSCALE_INV, b_out[sc]);
        float z = fmaf(acc1[reg], WSCALE_INV, b_out[32 + sc]) + 2.0f;
        float s = 1.0f / (1.0f + __expf(-z)) + 0.001f;
        int tc = 2 * sc + par;
        xr[tc] = xr[tc] * s + shiftv;
        ld += __logf(s);
    }
    return ld;
}

template<bool PACKED>
__global__ __launch_bounds__(1024) void flow_kernel(
    const float* __restrict__ inputs,
    const float* __restrict__ ctx,
    const float* __restrict__ W_in,  const float* __restrict__ b_in,
    const float* __restrict__ W_h,   const float* __restrict__ b_h,
    const float* __restrict__ W_out, const float* __restrict__ b_out,
    const int*   __restrict__ perms,
    const uchar* __restrict__ wpk,
    float* __restrict__ out)
{
    __shared__ __align__(16) uchar hbuf0[64 * RS];   // 33,280 B
    __shared__ __align__(16) uchar hbuf1[64 * RS];   // 33,280 B
    __shared__ __align__(16) uchar abuf[64 * AST];   // 10,752 B  [id|ctx]
    __shared__ __align__(16) float xbuf[64 * XST];   // 17,408 B
    __shared__ int permsh[NF];

    float* scratch = (float*)hbuf1;   // perm scratch (dead after G2)

    const int tid  = threadIdx.x;
    const int wave = tid >> 6;        // 0..15
    const int lane = tid & 63;
    const int trow = tid >> 4;        // 0..63
    const int tq   = tid & 15;        // 0..15
    const int row0 = blockIdx.x * 64;

    // ---- load + clip x tile into strided xbuf
    {
        float4 v = ((const float4*)(inputs + (size_t)row0 * NF))[tid];
        v.x = fminf(fmaxf(v.x, -1.f), 1.f);
        v.y = fminf(fmaxf(v.y, -1.f), 1.f);
        v.z = fminf(fmaxf(v.z, -1.f), 1.f);
        v.w = fminf(fmaxf(v.w, -1.f), 1.f);
        *(float4*)(xbuf + trow * XST + tq * 4) = v;
    }
    // ---- stage ctx ONCE (layer-invariant cols 32..159 of abuf)
    {
        const float* crow = ctx + (size_t)(row0 + trow) * NCTX + tq * 8;
        float4 f0 = ((const float4*)crow)[0];
        float4 f1 = ((const float4*)crow)[1];
        uint2 ck;
        ck.x = pk2<false>(f0.x, f0.y, 0u);
        ck.x = pk2<true >(f0.z, f0.w, ck.x);
        ck.y = pk2<false>(f1.x, f1.y, 0u);
        ck.y = pk2<true >(f1.z, f1.w, ck.y);
        *(uint2*)(abuf + trow * AST + 32 + tq * 8) = ck;
    }
    float ld_acc = 0.f;
    __syncthreads();

#pragma unroll 1
    for (int i = 0; i < NL; ++i) {
        const int par = i & 1;
        const int idp = par ^ 1;

        // ---- stage id cols (0..31) of abuf
        if (tq < 4) {
            const float* xr = xbuf + trow * XST + idp;
            uint2 idv;
            idv.x = pk2<false>(xr[2 * (tq * 8 + 0)], xr[2 * (tq * 8 + 1)], 0u);
            idv.x = pk2<true >(xr[2 * (tq * 8 + 2)], xr[2 * (tq * 8 + 3)], idv.x);
            idv.y = pk2<false>(xr[2 * (tq * 8 + 4)], xr[2 * (tq * 8 + 5)], 0u);
            idv.y = pk2<true >(xr[2 * (tq * 8 + 6)], xr[2 * (tq * 8 + 7)], idv.y);
            *(uint2*)(abuf + trow * AST + tq * 8) = idv;
        }
        __syncthreads();

        // ---- G0: K=160 (abuf -> hbuf0)
        gemm32T<10, PACKED>(
            PACKED ? wpk + OFF_WIN + (size_t)i * WIN_EPL : (const uchar*)0,
            W_in + (size_t)i * WIN_EPL, b_in + i * 512,
            abuf, AST, hbuf0, RS, wave, lane);
        __syncthreads();
        // ---- G1 (hbuf0 -> hbuf1)
        gemm32T<32, PACKED>(
            PACKED ? wpk + OFF_WH + (size_t)(i * 2 + 0) * WH_EPB : (const uchar*)0,
            W_h + (size_t)(i * 2 + 0) * WH_EPB, b_h + (i * 2 + 0) * 512,
            hbuf0, RS, hbuf1, RS, wave, lane);
        __syncthreads();
        // ---- G2 (hbuf1 -> hbuf0)
        gemm32T<32, PACKED>(
            PACKED ? wpk + OFF_WH + (size_t)(i * 2 + 1) * WH_EPB : (const uchar*)0,
            W_h + (size_t)(i * 2 + 1) * WH_EPB, b_h + (i * 2 + 1) * 512,
            hbuf1, RS, hbuf0, RS, wave, lane);
        __syncthreads();
        // ---- G3 + coupling (2 waves; in-register p, updates xbuf)
        if (wave < 2) {
            ld_acc += gemm3_couple<PACKED>(
                PACKED ? wpk + OFF_WOUT + (size_t)i * WOUT_EPL : (const uchar*)0,
                W_out + (size_t)i * WOUT_EPL, b_out + i * 64,
                hbuf0, xbuf, par, wave, lane);
        }
        __syncthreads();

        // ---- permutation
        if (i < NL - 1) {
            *(float4*)(scratch + trow * 64 + tq * 4) =
                *(const float4*)(xbuf + trow * XST + tq * 4);
            if (tid < NF) permsh[tid] = perms[i * NF + tid];
            __syncthreads();
#pragma unroll
            for (int j = 0; j < 4; ++j) {
                int c = tq * 4 + j;
                xbuf[trow * XST + c] = scratch[trow * 64 + permsh[c]];
            }
            __syncthreads();
        }
    }

    // ---- outputs: clip(x) then logdet
    {
        float4 v = *(const float4*)(xbuf + trow * XST + tq * 4);
        v.x = fminf(fmaxf(v.x, -1.f), 1.f);
        v.y = fminf(fmaxf(v.y, -1.f), 1.f);
        v.z = fminf(fmaxf(v.z, -1.f), 1.f);
        v.w = fminf(fmaxf(v.w, -1.f), 1.f);
        ((float4*)(out + (size_t)row0 * NF))[tid] = v;
    }
    // logdet: halves of each batch row live in lanes l and l+32 of waves 0/1
    ld_acc += __shfl_down(ld_acc, 32);
    if (wave < 2 && lane < 32)
        out[(size_t)BATCH * NF + row0 + wave * 32 + lane] = ld_acc;
}

extern "C" void kernel_launch(void* const* d_in, const int* in_sizes, int n_in,
                              void* d_out, int out_size, void* d_ws, size_t ws_size,
                              hipStream_t stream) {
    const float* inputs  = (const float*)d_in[0];
    const float* context = (const float*)d_in[1];
    const float* W_in    = (const float*)d_in[2];
    const float* b_in    = (const float*)d_in[3];
    const float* W_h     = (const float*)d_in[4];
    const float* b_h     = (const float*)d_in[5];
    const float* W_out   = (const float*)d_in[6];
    const float* b_out   = (const float*)d_in[7];
    const int*   perms   = (const int*)d_in[8];
    float* out = (float*)d_out;

    if (ws_size >= (size_t)NEED_WS) {
        uchar* ws = (uchar*)d_ws;
        const int total_threads = (int)(TOT_PACK_ELEMS / 8);    // 638976
        pack_weights_kernel<<<(total_threads + 255) / 256, 256, 0, stream>>>(
            W_in, W_h, W_out, ws);
        flow_kernel<true><<<256, 1024, 0, stream>>>(
            inputs, context, W_in, b_in, W_h, b_h, W_out, b_out, perms, ws, out);
    } else {
        flow_kernel<false><<<256, 1024, 0, stream>>>(
            inputs, context, W_in, b_in, W_h, b_h, W_out, b_out, perms,
            (const uchar*)0, out);
    }
}